// Round 10
// baseline (237.897 us; speedup 1.0000x reference)
//
#include <hip/hip_runtime.h>

// GuidedFilterND: I (8,4,768,768) f32 guide, p (8,1,768,768) f32 input, r=8, eps=1e-4.
// Stage A: box-filter 19 product channels, per-pixel 4x4 SPD solve -> (As,b) float2 + sumI (ws)
// Stage B: box-filter (As,b); q = (f(As)*sumI + f(b)) / N
// Round 15: SOFTWARE PREFETCH past the fences. Diagnosis: the asm("memory") LDS
//   fences pin the per-row rolling global loads -- the compiler cannot hoist row
//   r+1's lead/trail loads above row r's fences, so every row serially exposes an
//   L3/HBM latency (~400-900cy). This is the common flaw behind stage A's ~100us
//   plateau (DS 50% + VALU 46% with zero overlap) and stage B's 100-112us
//   invariance across 4 structures (its fastest variant was the burst one with
//   ONE latency exposure per 8 rows). Fix: issue row r+1's loads at the TOP of
//   iteration r (before any fence), consume row r from registers. Everything else
//   byte-identical to round 14 (phases, guards, math order -> same absmax).

#define HH 768
#define WW 768
#define CC 4
#define BB 8
#define RR 8
#define EPSF 1.0e-4f

// ---- stage A geometry (round-12 proven): 1 wave/block, 2 cols/lane ----
#define TA 64
#define LN 64
#define OUTA 112             // output cols per wave (lanes 4..59, 2 each)
#define NBANDA 7             // ceil(768/112)
#define SHA 16
#define NSTRIPEA (HH / SHA)  // 48

// ---- stage B geometry: stage-A clone ----
#define SHB 16
#define NSTRIPEB (HH / SHB)  // 48

// Intra-wave LDS sync: wait this wave's own LDS ops (lgkm only; no vmcnt drain).
// "memory" clobber = compiler fence: no memory access may be moved across it --
// which is exactly why prefetches must be ISSUED before it in program order.
__device__ __forceinline__ void wave_lds_sync() {
  asm volatile("s_waitcnt lgkmcnt(0)" ::: "memory");
}

// Raw 5-vector fetch for one row-pair (4 guide channels + p), no arithmetic.
__device__ __forceinline__ void fetch5(const float* __restrict__ Ib,
                                       const float* __restrict__ pb,
                                       int row, int col, float2 v[5]) {
  const int off = row * WW + col;
  const int chs = HH * WW;
  v[0] = *(const float2*)(Ib + off);
  v[1] = *(const float2*)(Ib + chs + off);
  v[2] = *(const float2*)(Ib + 2 * chs + off);
  v[3] = *(const float2*)(Ib + 3 * chs + off);
  v[4] = *(const float2*)(pb + off);
}

// Accumulate both columns' 19-channel sums from preloaded vectors; returns sumI pair.
template<bool ADD>
__device__ __forceinline__ float2 accum_vecs(const float2 v[5],
                                             float* __restrict__ s0,
                                             float* __restrict__ s1) {
  float pr[19];
  float i0 = v[0].x, i1 = v[1].x, i2 = v[2].x, i3 = v[3].x, pv = v[4].x;
  pr[0] = i0; pr[1] = i1; pr[2] = i2; pr[3] = i3;
  pr[4] = pv;
  pr[5] = pv * i0; pr[6] = pv * i1; pr[7] = pv * i2; pr[8] = pv * i3;
  pr[9]  = i0 * i0; pr[10] = i0 * i1; pr[11] = i0 * i2; pr[12] = i0 * i3;
  pr[13] = i1 * i1; pr[14] = i1 * i2; pr[15] = i1 * i3;
  pr[16] = i2 * i2; pr[17] = i2 * i3;
  pr[18] = i3 * i3;
#pragma unroll
  for (int k = 0; k < 19; ++k) { if (ADD) s0[k] += pr[k]; else s0[k] -= pr[k]; }
  float se = i0 + i1 + i2 + i3;
  i0 = v[0].y; i1 = v[1].y; i2 = v[2].y; i3 = v[3].y; pv = v[4].y;
  pr[0] = i0; pr[1] = i1; pr[2] = i2; pr[3] = i3;
  pr[4] = pv;
  pr[5] = pv * i0; pr[6] = pv * i1; pr[7] = pv * i2; pr[8] = pv * i3;
  pr[9]  = i0 * i0; pr[10] = i0 * i1; pr[11] = i0 * i2; pr[12] = i0 * i3;
  pr[13] = i1 * i1; pr[14] = i1 * i2; pr[15] = i1 * i3;
  pr[16] = i2 * i2; pr[17] = i2 * i3;
  pr[18] = i3 * i3;
#pragma unroll
  for (int k = 0; k < 19; ++k) { if (ADD) s1[k] += pr[k]; else s1[k] -= pr[k]; }
  float so = i0 + i1 + i2 + i3;
  return make_float2(se, so);
}

__device__ __forceinline__ float2 gf_solve(const float* __restrict__ h, float invN) {
  float Im0 = h[0] * invN, Im1 = h[1] * invN, Im2 = h[2] * invN, Im3 = h[3] * invN;
  float pm = h[4] * invN;
  float ft0 = h[5] * invN - pm * Im0;
  float ft1 = h[6] * invN - pm * Im1;
  float ft2 = h[7] * invN - pm * Im2;
  float ft3 = h[8] * invN - pm * Im3;
  float m[4][4];
  m[0][0] = h[9]  * invN + EPSF;
  m[0][1] = h[10] * invN;
  m[0][2] = h[11] * invN;
  m[0][3] = h[12] * invN;
  m[1][1] = h[13] * invN + EPSF;
  m[1][2] = h[14] * invN;
  m[1][3] = h[15] * invN;
  m[2][2] = h[16] * invN + EPSF;
  m[2][3] = h[17] * invN;
  m[3][3] = h[18] * invN + EPSF;
  m[1][0] = m[0][1]; m[2][0] = m[0][2]; m[3][0] = m[0][3];
  m[2][1] = m[1][2]; m[3][1] = m[1][3]; m[3][2] = m[2][3];
  float y[4] = {1.0f, 1.0f, 1.0f, 1.0f};
#pragma unroll
  for (int k = 0; k < 4; ++k) {
    float piv = 1.0f / m[k][k];
#pragma unroll
    for (int j = 0; j < 4; ++j) m[k][j] *= piv;
    y[k] *= piv;
#pragma unroll
    for (int i = 0; i < 4; ++i) {
      if (i == k) continue;
      float f = m[i][k];
#pragma unroll
      for (int j = 0; j < 4; ++j) m[i][j] -= f * m[k][j];
      y[i] -= f * y[k];
    }
  }
  float Asum = ft0 * y[0] + ft1 * y[1] + ft2 * y[2] + ft3 * y[3];
  float bv = pm - Asum * (Im0 + Im1 + Im2 + Im3);
  return make_float2(Asum, bv);
}

__global__ __launch_bounds__(TA, 2) void gf_stageA(const float* __restrict__ I,
                                                   const float* __restrict__ p,
                                                   float2* __restrict__ AB,
                                                   float* __restrict__ sumI_ws,
                                                   int storeSum) {
  // two 20-float slots per lane (80 B rows, b128, measured conflict-free):
  // SP = pair sums P, SL = even-column (lo) sums. 10240 B -> 16-block LDS cap.
  __shared__ float SP[LN][20];
  __shared__ float SL[LN][20];
  const int t = threadIdx.x;
  const int band0 = (int)blockIdx.x * OUTA;   // first output col of this wave
  const int c0 = band0 - 8 + 2 * t;           // this lane's even col
  const bool ok = (c0 >= 0) && (c0 < WW);     // pair-granular (boundaries even)
  const int r0 = (int)blockIdx.y * SHA;
  const int batch = (int)blockIdx.z;

  const float* Ib = I + (size_t)batch * CC * HH * WW;
  const float* pb = p + (size_t)batch * HH * WW;
  float* sIb = sumI_ws + (size_t)batch * HH * WW;
  float2* ABb = AB + (size_t)batch * HH * WW;

  float s0[19], s1[19];
#pragma unroll
  for (int k = 0; k < 19; ++k) { s0[k] = 0.0f; s1[k] = 0.0f; }

  // warm-up: preload window of row (r0-1) = rows [r0-RR-1, r0+RR-1] clipped.
  {
    int rlo = r0 - RR - 1; if (rlo < 0) rlo = 0;
    for (int row = rlo; row < r0 + RR; ++row) {
      if (ok) {
        float2 v[5]; fetch5(Ib, pb, row, c0, v);
        float2 f = accum_vecs<true>(v, s0, s1);
        // rows 0..7 are only ever touched by stripe 0's warm-up: store sumI here
        if (storeSum && r0 == 0)
          *(float2*)(&sIb[row * WW + c0]) = f;
      }
    }
  }

  const int ec = c0;
  const bool outok = (t >= 4) && (t <= 59) && (ec < WW);
  const int nwe = min(ec + RR, WW - 1) - max(ec - RR, 0) + 1;
  const int nwo = min(ec + 1 + RR, WW - 1) - max(ec + 1 - RR, 0) + 1;

  // pipeline prologue: raw vectors for iteration r0 (lead row r0+RR, trail r0-RR-1)
  float2 L[5], T[5], Ln[5], Tn[5];
#pragma unroll
  for (int k = 0; k < 5; ++k) {
    L[k] = make_float2(0.0f, 0.0f); T[k] = L[k]; Ln[k] = L[k]; Tn[k] = L[k];
  }
  {
    int rl = r0 + RR;       if (rl < HH && ok) fetch5(Ib, pb, rl, c0, L);
    int rt = r0 - RR - 1;   if (rt >= 0 && ok) fetch5(Ib, pb, rt, c0, T);
  }

  for (int r = r0; r < r0 + SHA; ++r) {
    // PREFETCH row r+1's loads FIRST -- issued before any fence of row r, so
    // their latency hides under this row's publish/taps/solve.
    if (r + 1 < r0 + SHA) {
      int rl = r + 1 + RR;  if (rl < HH && ok) fetch5(Ib, pb, rl, c0, Ln);
      int rt = r - RR;      if (rt >= 0 && ok) fetch5(Ib, pb, rt, c0, Tn);
    }
    // consume current row from registers
    {
      int rl = r + RR;
      if (rl < HH && ok) {
        float2 f = accum_vecs<true>(L, s0, s1);
        if (storeSum) *(float2*)(&sIb[rl * WW + c0]) = f;
      }
      int rt = r - RR - 1;
      if (rt >= 0 && ok) accum_vecs<false>(T, s0, s1);
    }
    // phase 0: publish P = s0+s1 and lo = s0 (10 x b128 writes)
    {
      float4* wp = (float4*)(&SP[t][0]);
      float4* wl = (float4*)(&SL[t][0]);
#pragma unroll
      for (int j = 0; j < 5; ++j) {
        float p0 = s0[4*j + 0] + s1[4*j + 0];
        float p1 = s0[4*j + 1] + s1[4*j + 1];
        float p2 = s0[4*j + 2] + s1[4*j + 2];
        float p3 = (4*j + 3 < 19) ? (s0[4*j + 3] + s1[4*j + 3]) : 0.0f;
        wp[j] = make_float4(p0, p1, p2, p3);
        wl[j] = make_float4(s0[4*j + 0], s0[4*j + 1], s0[4*j + 2],
                            (4*j + 3 < 19) ? s0[4*j + 3] : 0.0f);
      }
    }
    wave_lds_sync();
    // phase 1: flat 8-tap pair sum + 2 lo taps (50 x b128 reads), both outputs.
    //   even (col ec):   he = sum_{k=-4..+3} P[t+k]  + lo[t+4]
    //   odd  (col ec+1): ho = he - lo[t-4] + P[t+4] - lo[t+4]
    if (outok) {
      const float4* Pm4 = (const float4*)(&SP[t - 4][0]);
      const float4* Pm3 = (const float4*)(&SP[t - 3][0]);
      const float4* Pm2 = (const float4*)(&SP[t - 2][0]);
      const float4* Pm1 = (const float4*)(&SP[t - 1][0]);
      const float4* Pp1 = (const float4*)(&SP[t + 1][0]);
      const float4* Pp2 = (const float4*)(&SP[t + 2][0]);
      const float4* Pp3 = (const float4*)(&SP[t + 3][0]);
      const float4* Pp4 = (const float4*)(&SP[t + 4][0]);
      const float4* Lm4 = (const float4*)(&SL[t - 4][0]);
      const float4* Lp4 = (const float4*)(&SL[t + 4][0]);
      float he[20], ho[20];
#pragma unroll
      for (int j = 0; j < 5; ++j) {
        float4 a = Pm4[j], b = Pm3[j], c = Pm2[j], d = Pm1[j];
        float4 e = Pp1[j], f = Pp2[j], g = Pp3[j], hq = Pp4[j];
        float4 lm = Lm4[j], lp = Lp4[j];
        float o0 = s0[4*j + 0] + s1[4*j + 0];
        float o1 = s0[4*j + 1] + s1[4*j + 1];
        float o2 = s0[4*j + 2] + s1[4*j + 2];
        float o3 = (4*j + 3 < 19) ? (s0[4*j + 3] + s1[4*j + 3]) : 0.0f;
        float e0 = a.x + b.x + c.x + d.x + o0 + e.x + f.x + g.x + lp.x;
        float e1 = a.y + b.y + c.y + d.y + o1 + e.y + f.y + g.y + lp.y;
        float e2 = a.z + b.z + c.z + d.z + o2 + e.z + f.z + g.z + lp.z;
        float e3 = a.w + b.w + c.w + d.w + o3 + e.w + f.w + g.w + lp.w;
        he[4*j + 0] = e0; ho[4*j + 0] = e0 - lm.x + hq.x - lp.x;
        he[4*j + 1] = e1; ho[4*j + 1] = e1 - lm.y + hq.y - lp.y;
        he[4*j + 2] = e2; ho[4*j + 2] = e2 - lm.z + hq.z - lp.z;
        he[4*j + 3] = e3; ho[4*j + 3] = e3 - lm.w + hq.w - lp.w;
      }
      const int nh = min(r + RR, HH - 1) - max(r - RR, 0) + 1;
      float2 eo = gf_solve(he, 1.0f / (float)(nh * nwe));
      float2 oo = gf_solve(ho, 1.0f / (float)(nh * nwo));
      // packed store: (A_e, b_e, A_o, b_o) -> one dwordx4 (ec even => 16B aligned)
      *(float4*)(&ABb[(size_t)r * WW + ec]) = make_float4(eo.x, eo.y, oo.x, oo.y);
    }
    // loop-tail fence: next phase-0 writes must not hoist above this row's reads.
    wave_lds_sync();
    // rotate pipeline registers
#pragma unroll
    for (int k = 0; k < 5; ++k) { L[k] = Ln[k]; T[k] = Tn[k]; }
  }
}

__global__ __launch_bounds__(TA, 2) void gf_stageB(const float* __restrict__ I,
                                                   const float2* __restrict__ AB,
                                                   const float* __restrict__ sumI_ws,
                                                   float* __restrict__ q, int useSum) {
  // one 20-float slot per lane (80 B rows, proven conflict-free); only [0..3] used:
  // (PA, PB, loA, loB). 5120 B/block.
  __shared__ float S[LN][20];
  const int t = threadIdx.x;
  const int band0 = (int)blockIdx.x * OUTA;
  const int c0 = band0 - 8 + 2 * t;           // this lane's even col
  const bool ok = (c0 >= 0) && (c0 < WW);
  const int r0 = (int)blockIdx.y * SHB;
  const int batch = (int)blockIdx.z;

  const float* ABf = (const float*)(AB + (size_t)batch * HH * WW);  // float view
  const float* sIb = sumI_ws + (size_t)batch * HH * WW;
  const float* Ib = I + (size_t)batch * CC * HH * WW;
  float* qb = q + (size_t)batch * HH * WW;

  // rolling vertical sums for both columns: even (A0,B0), odd (A1,B1)
  float sA0 = 0.0f, sB0 = 0.0f, sA1 = 0.0f, sB1 = 0.0f;

  // warm-up rows [r0-RR-1, r0+RR-1] clipped, chunked-burst (MLP)
  {
    int rlo = r0 - RR - 1; if (rlo < 0) rlo = 0;
    const int rhi = r0 + RR;                   // exclusive
    for (int base = rlo; base < rhi; base += 8) {
      float4 wv[8];
      const int n = min(8, rhi - base);
#pragma unroll
      for (int k = 0; k < 8; ++k) {
        wv[k] = (k < n && ok)
                  ? *(const float4*)(ABf + ((size_t)(base + k) * WW + c0) * 2)
                  : make_float4(0.0f, 0.0f, 0.0f, 0.0f);
      }
#pragma unroll
      for (int k = 0; k < 8; ++k) {
        sA0 += wv[k].x; sB0 += wv[k].y; sA1 += wv[k].z; sB1 += wv[k].w;
      }
    }
  }

  const int ec = c0;
  const bool outok = (t >= 4) && (t <= 59) && (ec < WW);
  const int nwe = min(ec + RR, WW - 1) - max(ec - RR, 0) + 1;
  const int nwo = min(ec + 1 + RR, WW - 1) - max(ec + 1 - RR, 0) + 1;

  // pipeline prologue: raw lead/trail vectors for iteration r0
  float4 Lb = make_float4(0.0f, 0.0f, 0.0f, 0.0f), Tb = Lb, Lbn = Lb, Tbn = Lb;
  {
    int rl = r0 + RR;       if (rl < HH && ok) Lb = *(const float4*)(ABf + ((size_t)rl * WW + c0) * 2);
    int rt = r0 - RR - 1;   if (rt >= 0 && ok) Tb = *(const float4*)(ABf + ((size_t)rt * WW + c0) * 2);
  }

  for (int r = r0; r < r0 + SHB; ++r) {
    // PREFETCH row r+1's lead/trail before any fence of row r
    if (r + 1 < r0 + SHB) {
      int rl = r + 1 + RR;  if (rl < HH && ok) Lbn = *(const float4*)(ABf + ((size_t)rl * WW + c0) * 2);
      int rt = r - RR;      if (rt >= 0 && ok) Tbn = *(const float4*)(ABf + ((size_t)rt * WW + c0) * 2);
    }
    // consume current row from registers
    {
      int rl = r + RR;
      if (rl < HH && ok) { sA0 += Lb.x; sB0 += Lb.y; sA1 += Lb.z; sB1 += Lb.w; }
      int rt = r - RR - 1;
      if (rt >= 0 && ok) { sA0 -= Tb.x; sB0 -= Tb.y; sA1 -= Tb.z; sB1 -= Tb.w; }
    }
    const float PA = sA0 + sA1;
    const float PB = sB0 + sB1;
    // phase 0: publish ONE b128 = (PA, PB, loA, loB)
    *(float4*)(&S[t][0]) = make_float4(PA, PB, sA0, sB0);
    wave_lds_sync();
    // phase 1: 8 b128 taps; lo[t-4]/lo[t+4] ride in the t-4 / t+4 taps.
    if (outok) {
      float4 a = *(const float4*)(&S[t - 4][0]);
      float4 b = *(const float4*)(&S[t - 3][0]);
      float4 c = *(const float4*)(&S[t - 2][0]);
      float4 d = *(const float4*)(&S[t - 1][0]);
      float4 e = *(const float4*)(&S[t + 1][0]);
      float4 f = *(const float4*)(&S[t + 2][0]);
      float4 g = *(const float4*)(&S[t + 3][0]);
      float4 h = *(const float4*)(&S[t + 4][0]);
      // even col: sum P over t-4..t+3, + lo[t+4]
      float heA = a.x + b.x + c.x + d.x + PA + e.x + f.x + g.x + h.z;
      float heB = a.y + b.y + c.y + d.y + PB + e.y + f.y + g.y + h.w;
      // odd col: even - lo[t-4] + P[t+4] - lo[t+4]
      float hoA = heA - a.z + h.x - h.z;
      float hoB = heB - a.w + h.y - h.w;
      const int nh = min(r + RR, HH - 1) - max(r - RR, 0) + 1;
      const float invNe = 1.0f / (float)(nh * nwe);
      const float invNo = 1.0f / (float)(nh * nwo);
      float sie, sio;
      if (useSum) {
        float2 si = *(const float2*)(&sIb[(size_t)r * WW + ec]);
        sie = si.x; sio = si.y;
      } else {
        const int off = r * WW + ec;
        const int chs = HH * WW;
        float2 i0 = *(const float2*)(Ib + off);
        float2 i1 = *(const float2*)(Ib + chs + off);
        float2 i2 = *(const float2*)(Ib + 2 * chs + off);
        float2 i3 = *(const float2*)(Ib + 3 * chs + off);
        sie = i0.x + i1.x + i2.x + i3.x;
        sio = i0.y + i1.y + i2.y + i3.y;
      }
      float qe = (heA * sie + heB) * invNe;
      float qo = (hoA * sio + hoB) * invNo;
      *(float2*)(&qb[(size_t)r * WW + ec]) = make_float2(qe, qo);
    }
    // loop-tail fence: next publish must not hoist above this row's tap reads.
    wave_lds_sync();
    // rotate pipeline registers
    Lb = Lbn; Tb = Tbn;
  }
}

extern "C" void kernel_launch(void* const* d_in, const int* in_sizes, int n_in,
                              void* d_out, int out_size, void* d_ws, size_t ws_size,
                              hipStream_t stream) {
  const float* I = (const float*)d_in[0];   // (8,4,768,768) f32
  const float* p = (const float*)d_in[1];   // (8,1,768,768) f32
  float* q = (float*)d_out;                 // (8,1,768,768) f32

  const size_t npix = (size_t)BB * HH * WW;
  float2* AB = (float2*)d_ws;                               // 37.75 MB
  float* sumI_ws = (float*)(AB + npix);                     // +18.87 MB
  const size_t need = npix * sizeof(float2) + npix * sizeof(float);
  const int useSum = (ws_size >= need) ? 1 : 0;             // constant across calls

  dim3 gridA(NBANDA, NSTRIPEA, BB);    // (7, 48, 8) = 2688 single-wave blocks
  dim3 gridB(NBANDA, NSTRIPEB, BB);    // (7, 48, 8) = 2688 single-wave blocks
  hipLaunchKernelGGL(gf_stageA, gridA, dim3(TA), 0, stream, I, p, AB, sumI_ws, useSum);
  hipLaunchKernelGGL(gf_stageB, gridB, dim3(TA), 0, stream, I, AB, sumI_ws, q, useSum);
}